// Round 7
// baseline (267.289 us; speedup 1.0000x reference)
//
#include <hip/hip_runtime.h>
#include <math.h>

// VectorQuantizer: argmin_k ||x_n - c_k||^2, N=32768, K=8192, D=64, fp32.
// Round-7: round-6 MFMA structure (3-plane bf16 split, 32x32x16, 2 chains,
// frag-ordered pre-split codebook) with the serial per-tile chain broken up:
//  * epilogue software-pipelined: epi(t-1) runs as independent VALU under
//    tile t's MFMAs (double accumulator sets, 2-step manual unroll).
//  * staging via global_load_lds into a 3-buffer rolling pipeline: DMA for
//    tile t+2 issued after tile t's ds_reads; manual s_waitcnt vmcnt(6|7) +
//    raw s_barrier at iter top. Every DMA has 2 iterations to land.
//  * ldsA gone (A-frags split from global straight into registers);
//    csq embedded in each swizzled tile (width-4 DMA chunk) so the per-wave
//    vmcnt FIFO stays uniform: 6 (waves 0-2) or 7 (wave 3) issues/iter.
// Numerics: identical dist formula fmaf(-2, accA+accB, xsq) + csq, strict <
// over ascending code, u64 (distbits<<32|code) cross-lane mins = numpy
// first-occurrence. (MFMA in-chain order is kc-major now; error scale
// unchanged ~1e-7 — 3 prior orderings all measured absmax 0.)

typedef __attribute__((ext_vector_type(8)))  short s8v;
typedef __attribute__((ext_vector_type(16))) float f16v;
typedef __attribute__((ext_vector_type(4)))  float f4v;

constexpr int NROWS = 32768;
constexpr int KC    = 8192;
constexpr int DD    = 64;
constexpr int TPB   = 256;                 // 4 waves
constexpr int BROWS = 64;                  // rows per block
constexpr int BTILE = 64;                  // codes per tile
constexpr int NT    = KC / BTILE;          // 128
constexpr int TSH     = 12416;             // shorts per tile (24832 B): 24 KB planes + 256 B csq + pad
constexpr int CSQ_OFF = 12288;             // short offset of csq floats within a tile

__device__ __forceinline__ short bf16_rne(float v, float& resid) {
  unsigned u = __float_as_uint(v);
  unsigned r = (u + 0x7FFFu + ((u >> 16) & 1u)) >> 16;
  resid = v - __uint_as_float(r << 16);   // exact
  return (short)r;
}
__device__ __forceinline__ void split3(float v, short& b1, short& b2, short& b3) {
  float r1, r2, r3;
  b1 = bf16_rne(v, r1);
  b2 = bf16_rne(r1, r2);
  b3 = bf16_rne(r2, r3);
}

__device__ __forceinline__ void dma16(const short* g, short* l) {
  __builtin_amdgcn_global_load_lds(
      (const __attribute__((address_space(1))) unsigned int*)g,
      (__attribute__((address_space(3))) unsigned int*)l, 16, 0, 0);
}
__device__ __forceinline__ void dma4(const short* g, short* l) {
  __builtin_amdgcn_global_load_lds(
      (const __attribute__((address_space(1))) unsigned int*)g,
      (__attribute__((address_space(3))) unsigned int*)l, 4, 0, 0);
}

// Pre-kernel: blocks [0,32): split cb into frag-ordered 3-plane tiles with
// embedded csq. blocks [32,160): xsq. Same sequential-fmaf chains as all
// passing rounds.
__global__ void vq_pre_kernel(const float* __restrict__ x,
                              const float* __restrict__ cb,
                              short* __restrict__ bSwz,
                              float* __restrict__ xsq) {
  const int bid = blockIdx.x, tid = threadIdx.x;
  if (bid < KC / TPB) {
    const int code = bid * TPB + tid;
    const float* cp = cb + (size_t)code * DD;
    float v[DD];
#pragma unroll
    for (int d = 0; d < DD; d += 4) {
      const float4 g = *(const float4*)(cp + d);
      v[d] = g.x; v[d + 1] = g.y; v[d + 2] = g.z; v[d + 3] = g.w;
    }
    float s = 0.f;
#pragma unroll
    for (int d = 0; d < DD; ++d) s = fmaf(v[d], v[d], s);
    short p1[DD], p2[DD], p3[DD];
#pragma unroll
    for (int d = 0; d < DD; ++d) split3(v[d], p1[d], p2[d], p3[d]);
    // Tile T (64 codes) = two 32-code groups; chunk (p,kc4) holds 64 lanes
    // x 8 bf16: lane (h*32+l) = code (g*32+l), k = kc4*16 + h*8 + j.
    const int T = code >> 6, sub = (code >> 5) & 1, l = code & 31;
    short* base = bSwz + (size_t)T * TSH + sub * 6144;
#pragma unroll
    for (int p = 0; p < 3; ++p) {
      const short* pl = (p == 0) ? p1 : (p == 1) ? p2 : p3;
#pragma unroll
      for (int kc4 = 0; kc4 < 4; ++kc4)
#pragma unroll
        for (int h = 0; h < 2; ++h) {
          s8v wv;
#pragma unroll
          for (int j = 0; j < 8; ++j) wv[j] = pl[kc4 * 16 + h * 8 + j];
          *(s8v*)(base + (p * 4 + kc4) * 512 + (h * 32 + l) * 8) = wv;
        }
    }
    ((float*)(bSwz + (size_t)T * TSH + CSQ_OFF))[code & 63] = s;
  } else {
    const int n = (bid - KC / TPB) * TPB + tid;
    const float* xp = x + (size_t)n * DD;
    float s = 0.f;
#pragma unroll
    for (int d = 0; d < DD; ++d) s = fmaf(xp[d], xp[d], s);
    xsq[n] = s;
  }
}

__global__ __launch_bounds__(TPB, 2)
void vq_mfma_kernel(const float* __restrict__ x, const short* __restrict__ bSwz,
                    const float* __restrict__ xsq_g, int* __restrict__ out) {
  __shared__ alignas(16) short ldsB[3][TSH];         // 74496 B
  __shared__ unsigned long long ldsRed[BROWS][2];    // 1024 B

  const int tid  = threadIdx.x;
  const int lane = tid & 63;
  const int w    = tid >> 6;
  const int s    = w & 1;        // row stripe (32 rows)
  const int ch   = w >> 1;       // code half (32 codes)
  const int half = lane >> 5;
  const int col  = lane & 31;
  const int blockRow = blockIdx.x * BROWS;

  // ---- A fragments straight from global (once): row = blockRow+s*32+col,
  // frag[p][kc4] = k in [kc4*16 + half*8, +8).
  s8v afr[3][4];
  {
    const float* xr = x + (size_t)(blockRow + s * 32 + col) * DD;
#pragma unroll
    for (int kc4 = 0; kc4 < 4; ++kc4) {
      const float* p8 = xr + kc4 * 16 + half * 8;
      const float4 a = *(const float4*)p8;
      const float4 b = *(const float4*)(p8 + 4);
      const float v[8] = {a.x, a.y, a.z, a.w, b.x, b.y, b.z, b.w};
      s8v q1, q2, q3;
#pragma unroll
      for (int e = 0; e < 8; ++e) {
        short t1, t2, t3; split3(v[e], t1, t2, t3);
        q1[e] = t1; q2[e] = t2; q3[e] = t3;
      }
      afr[0][kc4] = q1; afr[1][kc4] = q2; afr[2][kc4] = q3;
    }
  }
  // xsq for this lane's 16 C-slots: row = s*32 + (i&3) + 8*(i>>2) + 4*half.
  float xq[16];
  {
    const float* xb = xsq_g + blockRow + s * 32 + 4 * half;
#pragma unroll
    for (int g8 = 0; g8 < 4; ++g8) {
      const float4 t4 = *(const float4*)(xb + g8 * 8);
      xq[g8 * 4] = t4.x; xq[g8 * 4 + 1] = t4.y;
      xq[g8 * 4 + 2] = t4.z; xq[g8 * 4 + 3] = t4.w;
    }
  }

  short* b0 = &ldsB[0][0];
  short* b1 = &ldsB[1][0];
  short* b2 = &ldsB[2][0];

  // DMA one tile: waves 0-2 cover chunks w*6..w*6+5; wave 3 chunks 18..23 +
  // the 256-B csq chunk. Per-wave issues/iter: 6 (w<3) or 7 (w==3).
  auto issue_tile = [&](int t, short* buf) {
    const short* g = bSwz + (size_t)t * TSH;
    if (w < 3) {
#pragma unroll
      for (int i = 0; i < 6; ++i) {
        const int c = w * 6 + i;
        dma16(g + c * 512 + lane * 8, buf + c * 512 + lane * 8);
      }
    } else {
#pragma unroll
      for (int i = 0; i < 6; ++i) {
        const int c = 18 + i;
        dma16(g + c * 512 + lane * 8, buf + c * 512 + lane * 8);
      }
      dma4(g + CSQ_OFF + lane * 2, buf + CSQ_OFF + lane * 2);
    }
  };

  issue_tile(0, b0);
  issue_tile(1, b1);

  const f16v zero16 = {0.f,0.f,0.f,0.f,0.f,0.f,0.f,0.f,
                       0.f,0.f,0.f,0.f,0.f,0.f,0.f,0.f};
  const f16v neg16  = {-1e30f,-1e30f,-1e30f,-1e30f,-1e30f,-1e30f,-1e30f,-1e30f,
                       -1e30f,-1e30f,-1e30f,-1e30f,-1e30f,-1e30f,-1e30f,-1e30f};
  f16v aA0, aB0, aA1 = neg16, aB1 = neg16;   // parity-1 inited: epi(-1) never selects
  float csOld = 0.f;
  float bestD[16];
  unsigned bestC[16];
#pragma unroll
  for (int i = 0; i < 16; ++i) { bestD[i] = INFINITY; bestC[i] = 0u; }

  // One tile body. Order: [wait][barrier] [csq+frag ds_reads][MFMA into W*]
  // [DMA t+2][epi(t-1) from R*][rotate]. Waits: need own D(t) done ->
  // vmcnt(6|7) leaves exactly one iteration's issues outstanding.
  auto body = [&](int t, short* bufR, short* bufW,
                  f16v& WA, f16v& WB, const f16v& RA, const f16v& RB) {
    if (w < 3) __builtin_amdgcn_s_waitcnt(0xF76);   // vmcnt(6), lgkm/exp no-wait
    else       __builtin_amdgcn_s_waitcnt(0xF77);   // vmcnt(7)
    __builtin_amdgcn_s_barrier();

    const float csNew = ((const float*)(bufR + CSQ_OFF))[ch * 32 + col];
    WA = zero16; WB = zero16;
#pragma unroll
    for (int kc = 0; kc < 4; ++kc) {
      const s8v f0 = *(const s8v*)(bufR + (ch * 12 + 0 * 4 + kc) * 512 + lane * 8);
      const s8v f1 = *(const s8v*)(bufR + (ch * 12 + 1 * 4 + kc) * 512 + lane * 8);
      const s8v f2 = *(const s8v*)(bufR + (ch * 12 + 2 * 4 + kc) * 512 + lane * 8);
      // Chain A: a1b1, a2b1, a2b2 ; Chain B: a1b2, a1b3, a3b1 (per kc).
      WA = __builtin_amdgcn_mfma_f32_32x32x16_bf16(afr[0][kc], f0, WA, 0, 0, 0);
      WB = __builtin_amdgcn_mfma_f32_32x32x16_bf16(afr[0][kc], f1, WB, 0, 0, 0);
      WA = __builtin_amdgcn_mfma_f32_32x32x16_bf16(afr[1][kc], f0, WA, 0, 0, 0);
      WB = __builtin_amdgcn_mfma_f32_32x32x16_bf16(afr[0][kc], f2, WB, 0, 0, 0);
      WA = __builtin_amdgcn_mfma_f32_32x32x16_bf16(afr[1][kc], f1, WA, 0, 0, 0);
      WB = __builtin_amdgcn_mfma_f32_32x32x16_bf16(afr[2][kc], f0, WB, 0, 0, 0);
    }

    issue_tile((t + 2) & (NT - 1), bufW);   // wrap keeps vmcnt FIFO uniform

    // Pipelined epilogue for tile t-1 (at t=0: R* = -1e30 -> dist ~ +4e30,
    // never selected; code underflow harmless).
    const unsigned codeBase = (unsigned)((t - 1) * BTILE + ch * 32 + col);
#pragma unroll
    for (int i = 0; i < 16; ++i) {
      const float dist = fmaf(-2.f, RA[i] + RB[i], xq[i]) + csOld;
      if (dist < bestD[i]) { bestD[i] = dist; bestC[i] = codeBase; }
    }
    csOld = csNew;
  };

  for (int t = 0; t < NT; t += 2) {
    body(t,     b0, b2, aA0, aB0, aA1, aB1);
    short* tmp0 = b0; b0 = b1; b1 = b2; b2 = tmp0;
    body(t + 1, b0, b2, aA1, aB1, aA0, aB0);
    short* tmp1 = b0; b0 = b1; b1 = b2; b2 = tmp1;
  }
  // Final epilogue for tile NT-1 (parity 1).
  {
    const unsigned codeBase = (unsigned)((NT - 1) * BTILE + ch * 32 + col);
#pragma unroll
    for (int i = 0; i < 16; ++i) {
      const float dist = fmaf(-2.f, aA1[i] + aB1[i], xq[i]) + csOld;
      if (dist < bestD[i]) { bestD[i] = dist; bestC[i] = codeBase; }
    }
  }

  // ---- Cross-lane reduce: u64 min over 32 cols per half, then halves.
  unsigned long long key[16];
#pragma unroll
  for (int i = 0; i < 16; ++i)
    key[i] = ((unsigned long long)__float_as_uint(bestD[i]) << 32) | bestC[i];
#pragma unroll
  for (int i = 0; i < 16; ++i) {
#pragma unroll
    for (int m = 1; m < 32; m <<= 1) {
      const unsigned long long o = __shfl_xor(key[i], m, 64);
      if (o < key[i]) key[i] = o;
    }
  }
  __syncthreads();            // also drains tail dummy DMAs
  if (col == 0) {
#pragma unroll
    for (int i = 0; i < 16; ++i) {
      const int row = s * 32 + (i & 3) + 8 * (i >> 2) + 4 * half;
      ldsRed[row][ch] = key[i];
    }
  }
  __syncthreads();
  if (tid < BROWS) {
    const unsigned long long a = ldsRed[tid][0];
    const unsigned long long b = ldsRed[tid][1];
    out[blockRow + tid] = (int)(unsigned)((a < b ? a : b) & 0xFFFFFFFFull);
  }
}

extern "C" void kernel_launch(void* const* d_in, const int* in_sizes, int n_in,
                              void* d_out, int out_size, void* d_ws, size_t ws_size,
                              hipStream_t stream) {
  const float* x  = (const float*)d_in[0];   // [N, 64] fp32
  const float* cb = (const float*)d_in[1];   // [K, 64] fp32
  int* out = (int*)d_out;                    // [N] int32

  // ws: bSwz tiles (128 x 24832 B = 3.18 MB) | xsq (128 KB)
  short* bSwz  = (short*)d_ws;
  float* xsq_g = (float*)((char*)d_ws + (size_t)NT * TSH * 2);

  vq_pre_kernel<<<dim3(KC / TPB + NROWS / TPB), dim3(TPB), 0, stream>>>(
      x, cb, bSwz, xsq_g);
  vq_mfma_kernel<<<dim3(NROWS / BROWS), dim3(TPB), 0, stream>>>(
      x, bSwz, xsq_g, out);
}